// Round 12
// baseline (244.126 us; speedup 1.0000x reference)
//
#include <hip/hip_runtime.h>
#include <hip/hip_bf16.h>

typedef __bf16 bf16x8 __attribute__((ext_vector_type(8)));
typedef float  f32x4  __attribute__((ext_vector_type(4)));

#define MFMA16 __builtin_amdgcn_mfma_f32_16x16x32_bf16

__device__ __forceinline__ float fast_tanh(float x) {
    float e = __builtin_amdgcn_exp2f(x * 2.8853900817779268f);
    return 1.0f - 2.0f * __builtin_amdgcn_rcpf(e + 1.0f);
}

// kappa permutation (within each 32-col block): stored k-index s -> phys col
__device__ __forceinline__ int kinv(int ke) {
    return (ke & ~31) | ((ke & 1) << 4) | ((ke >> 1) & 15);
}

__device__ __forceinline__ bf16x8 cvt2(const float4 a, const float4 b) {
    bf16x8 t;
    t[0] = (__bf16)a.x; t[1] = (__bf16)a.y; t[2] = (__bf16)a.z; t[3] = (__bf16)a.w;
    t[4] = (__bf16)b.x; t[5] = (__bf16)b.y; t[6] = (__bf16)b.z; t[7] = (__bf16)b.w;
    return t;
}

// ---- weight pre-conversion: f32 -> bf16 MFMA B-fragments in d_ws ----
// table1 ws[0,131072):      [cb:16][kk:8][lane:64][j:8 bf16]  (GEMM1, phys rows)
// table2 ws[131072,196608): [q4:4][kk:8][nbl:2][lane:64][j:8] (GEMM2, kappa rows)
// table3 ws[196608,212992): [nb:4][kk:4][lane:64][j:8]        (GEMM3, kappa rows)
__global__ __launch_bounds__(256) void preconv_kernel(
    const float* __restrict__ WFOH, const float* __restrict__ WFOM,
    const float* __restrict__ rhid2Layer, const float* __restrict__ routLayer,
    char* __restrict__ ws)
{
    const int f = blockIdx.x * 256 + threadIdx.x;
    bf16x8 v;
    char* dst;
    if (f < 8192) {
        const int lane = f & 63, t = f >> 6;
        const int kk = t & 7, cb = t >> 3;
        const int g = lane >> 4, c = lane & 15;
        const float* Wsrc = (cb < 8) ? WFOH : WFOM;
        const int col = (16 * cb + c) & 127;
        #pragma unroll
        for (int j = 0; j < 8; ++j) v[j] = (__bf16)Wsrc[(32 * kk + 8 * g + j) * 128 + col];
        dst = ws + (size_t)f * 16;
    } else if (f < 12288) {
        const int f2 = f - 8192;
        const int lane = f2 & 63, t = f2 >> 6;
        const int nbl = t & 1, kk = (t >> 1) & 7, q4 = t >> 4;
        const int g = lane >> 4, c = lane & 15;
        const int n2 = 32 * q4 + 16 * nbl + c;
        #pragma unroll
        for (int j = 0; j < 8; ++j) v[j] = (__bf16)rhid2Layer[kinv(32 * kk + 8 * g + j) * 128 + n2];
        dst = ws + 131072 + (size_t)f2 * 16;
    } else if (f < 13312) {
        const int f3 = f - 12288;
        const int lane = f3 & 63, t = f3 >> 6;
        const int kk = t & 3, nb = t >> 2;
        const int g = lane >> 4, c = lane & 15;
        const int n3 = 16 * nb + c;
        #pragma unroll
        for (int j = 0; j < 8; ++j) v[j] = (__bf16)routLayer[kinv(32 * kk + 8 * g + j) * 64 + n3];
        dst = ws + 196608 + (size_t)f3 * 16;
    } else {
        return;
    }
    *(bf16x8*)dst = v;
}

template<bool PRE>
__device__ __forceinline__ bf16x8 wfrag1(const char* ws, const float* WFOH, const float* WFOM,
                                         int cb, int kk, int lane) {
    if constexpr (PRE) {
        return *(const bf16x8*)(ws + (size_t)cb * 8192 + kk * 1024 + lane * 16);
    } else {
        const int g = lane >> 4, c = lane & 15;
        const float* Wsrc = (cb < 8) ? WFOH : WFOM;
        const int col = (16 * cb + c) & 127;
        bf16x8 v;
        #pragma unroll
        for (int j = 0; j < 8; ++j) v[j] = (__bf16)Wsrc[(32 * kk + 8 * g + j) * 128 + col];
        return v;
    }
}
template<bool PRE>
__device__ __forceinline__ bf16x8 wfrag2(const char* ws, const float* rhid2Layer,
                                         int q4, int kk, int nbl, int lane) {
    if constexpr (PRE) {
        return *(const bf16x8*)(ws + 131072 + (size_t)q4 * 16384 + kk * 2048 + nbl * 1024 + lane * 16);
    } else {
        const int g = lane >> 4, c = lane & 15;
        const int n2 = 32 * q4 + 16 * nbl + c;
        bf16x8 v;
        #pragma unroll
        for (int j = 0; j < 8; ++j) v[j] = (__bf16)rhid2Layer[kinv(32 * kk + 8 * g + j) * 128 + n2];
        return v;
    }
}
template<bool PRE>
__device__ __forceinline__ bf16x8 wfrag3(const char* ws, const float* routLayer,
                                         int nb, int kk, int lane) {
    if constexpr (PRE) {
        return *(const bf16x8*)(ws + 196608 + (size_t)nb * 4096 + kk * 1024 + lane * 16);
    } else {
        const int g = lane >> 4, c = lane & 15;
        const int n3 = 16 * nb + c;
        bf16x8 v;
        #pragma unroll
        for (int j = 0; j < 8; ++j) v[j] = (__bf16)routLayer[kinv(32 * kk + 8 * g + j) * 64 + n3];
        return v;
    }
}

// Convoyed wave-independent kernel: 256 threads = 4 waves, each owning 16
// edges end-to-end (no data sharing). Raw s_barrier (no waitcnt — pure
// convoy, correct since nothing is shared) keeps the 4 waves reading the
// same weight-fragment stream within an L1-sized window: 3/4 L1 hits.
// 8KB wave-private LDS; 32KB/block -> LDS allows 5 blocks/CU (20 waves).
template<bool PRE>
__global__ __launch_bounds__(256, 2) void rel_kernel(
    const float* __restrict__ fwd, const float* __restrict__ bwd,
    const int* __restrict__ gold_heads, const int* __restrict__ gold_rels,
    const float* __restrict__ WFOH, const float* __restrict__ WFOM,
    const float* __restrict__ rcatBias, const float* __restrict__ rhid2Layer,
    const float* __restrict__ rhid2Bias, const float* __restrict__ routLayer,
    const float* __restrict__ routBias, const char* __restrict__ wstab,
    int* __restrict__ fixcnt, int* __restrict__ fixlist, int fixcap,
    float* __restrict__ out, int E, int NT16)
{
    __shared__ __align__(16) char smem[32768];
    const int tid   = threadIdx.x;
    const int w     = tid >> 6;          // 0..3
    const int lane  = tid & 63;
    const int row16 = lane & 15;
    const int g     = lane >> 4;
    char* const myh = smem + w * 8192;   // wave-private scratch

    // uniform trip count across the block (barriers inside the loop)
    for (int base = blockIdx.x * 4; base < NT16; base += gridDim.x * 4) {
        const int tile = base + w;
        const int e0 = tile * 16;

        // laundered pointers: keep weight/bias loads inside the tile loop
        int zoff = 0;
        asm volatile("" : "+v"(zoff));
        const char*  wsL  = wstab + zoff;
        const float* W1aL = WFOH + zoff;
        const float* W1bL = WFOM + zoff;
        const float* W2L  = rhid2Layer + zoff;
        const float* W3L  = routLayer + zoff;
        const float* rcL  = rcatBias + zoff;
        const float* r2L  = rhid2Bias + zoff;
        const float* roL  = routBias + zoff;

        // ---- cat A-frags directly from global (lane = row row16) ----
        const int er = e0 + row16;
        const bool ev = er < E;
        const int head = ev ? gold_heads[er] : 0;
        const float* frow = fwd + (size_t)head * 128;
        const float* brow = bwd + (ev ? (size_t)(er + 1) * 128 : (size_t)0);
        bf16x8 a[8];
        #pragma unroll
        for (int kk = 0; kk < 4; ++kk) {
            const float4* p = (const float4*)(frow + 32 * kk + 8 * g);
            a[kk] = cvt2(p[0], p[1]);
        }
        #pragma unroll
        for (int kk = 0; kk < 4; ++kk) {
            const float4* p = (const float4*)(brow + 32 * kk + 8 * g);
            a[4 + kk] = cvt2(p[0], p[1]);
        }

        __builtin_amdgcn_s_barrier();     // convoy: align weight streams (GEMM1)

        // ---- GEMM1: h(16x256), two n-halves of 8 col-blocks ----
        #pragma unroll
        for (int half = 0; half < 2; ++half) {
            f32x4 acc[8];
            #pragma unroll
            for (int j = 0; j < 8; ++j) {
                const float b = rcL[16 * (8 * half + j) + row16];   // bias-splat init
                acc[j] = (f32x4){b, b, b, b};
            }
            __builtin_amdgcn_s_setprio(1);
            #pragma unroll
            for (int kk = 0; kk < 8; ++kk) {
                #pragma unroll
                for (int j = 0; j < 8; ++j) {
                    const bf16x8 b = wfrag1<PRE>(wsL, W1aL, W1bL, 8 * half + j, kk, lane);
                    acc[j] = MFMA16(a[kk], b, acc[j], 0, 0, 0);
                }
            }
            __builtin_amdgcn_s_setprio(0);
            // tanh + kappa-pack -> wave-private LDS (rows 512B, rotation swizzle)
            #pragma unroll
            for (int q = 0; q < 4; ++q) {
                const int qq = 4 * half + q;
                #pragma unroll
                for (int r = 0; r < 4; ++r) {
                    const int row = 4 * g + r;
                    const __bf16 p0 = (__bf16)fast_tanh(acc[2 * q][r]);
                    const __bf16 p1 = (__bf16)fast_tanh(acc[2 * q + 1][r]);
                    const unsigned uval = (unsigned)__builtin_bit_cast(unsigned short, p0)
                                        | ((unsigned)__builtin_bit_cast(unsigned short, p1) << 16);
                    const int u = 4 * qq + (row16 >> 2);
                    *(unsigned*)(myh + row * 512 + 16 * ((u + row) & 31) + 4 * (row16 & 3)) = uval;
                }
            }
        }

        // ---- h A-frags back from LDS (same wave: lgkmcnt only) ----
        #pragma unroll
        for (int kk = 0; kk < 8; ++kk)
            a[kk] = *(const bf16x8*)(myh + row16 * 512 + 16 * ((4 * kk + g + row16) & 31));

        __builtin_amdgcn_s_barrier();     // convoy (GEMM2)

        // ---- GEMM2: h2(16x128), 8 col-blocks ----
        f32x4 acc2[8];
        #pragma unroll
        for (int j = 0; j < 8; ++j) {
            const float b = r2L[16 * j + row16];
            acc2[j] = (f32x4){b, b, b, b};
        }
        __builtin_amdgcn_s_setprio(1);
        #pragma unroll
        for (int kk = 0; kk < 8; ++kk) {
            #pragma unroll
            for (int j = 0; j < 8; ++j) {
                const bf16x8 b = wfrag2<PRE>(wsL, W2L, j >> 1, kk, j & 1, lane);
                acc2[j] = MFMA16(a[kk], b, acc2[j], 0, 0, 0);
            }
        }
        __builtin_amdgcn_s_setprio(0);
        // tanh + kappa-pack h2 into myh (rows 256B now; h region dead)
        #pragma unroll
        for (int q = 0; q < 4; ++q) {
            #pragma unroll
            for (int r = 0; r < 4; ++r) {
                const int row = 4 * g + r;
                const __bf16 p0 = (__bf16)fast_tanh(acc2[2 * q][r]);
                const __bf16 p1 = (__bf16)fast_tanh(acc2[2 * q + 1][r]);
                const unsigned uval = (unsigned)__builtin_bit_cast(unsigned short, p0)
                                    | ((unsigned)__builtin_bit_cast(unsigned short, p1) << 16);
                const int u2 = 4 * q + (row16 >> 2);
                *(unsigned*)(myh + row * 256 + 16 * ((u2 + row) & 15) + 4 * (row16 & 3)) = uval;
            }
        }

        // ---- h2 A-frags ----
        bf16x8 a3[4];
        #pragma unroll
        for (int kk = 0; kk < 4; ++kk)
            a3[kk] = *(const bf16x8*)(myh + row16 * 256 + 16 * ((4 * kk + g + row16) & 15));

        __builtin_amdgcn_s_barrier();     // convoy (GEMM3)

        // ---- GEMM3: sc(16x64) + in-wave hinge ----
        f32x4 acc3[4];
        #pragma unroll
        for (int j = 0; j < 4; ++j) {
            const float b = roL[16 * j + row16];
            acc3[j] = (f32x4){b, b, b, b};
        }
        __builtin_amdgcn_s_setprio(1);
        #pragma unroll
        for (int kk = 0; kk < 4; ++kk) {
            #pragma unroll
            for (int j = 0; j < 4; ++j) {
                const bf16x8 b = wfrag3<PRE>(wsL, W3L, j, kk, lane);
                acc3[j] = MFMA16(a3[kk], b, acc3[j], 0, 0, 0);
            }
        }
        __builtin_amdgcn_s_setprio(0);
        #pragma unroll
        for (int r = 0; r < 4; ++r) {
            const int e = e0 + 4 * g + r;
            const int gold = (e < E) ? gold_rels[e] : 0;
            float gs = -3.0e38f, ws_ = -3.0e38f;
            #pragma unroll
            for (int nb = 0; nb < 4; ++nb) {
                const float v = acc3[nb][r];
                const int lab = 16 * nb + row16;
                if (lab == gold) gs = v; else ws_ = fmaxf(ws_, v);
            }
            gs = fmaxf(gs, __shfl_xor(gs, 1)); ws_ = fmaxf(ws_, __shfl_xor(ws_, 1));
            gs = fmaxf(gs, __shfl_xor(gs, 2)); ws_ = fmaxf(ws_, __shfl_xor(ws_, 2));
            gs = fmaxf(gs, __shfl_xor(gs, 4)); ws_ = fmaxf(ws_, __shfl_xor(ws_, 4));
            gs = fmaxf(gs, __shfl_xor(gs, 8)); ws_ = fmaxf(ws_, __shfl_xor(ws_, 8));
            if (row16 == 0 && e < E) {
                out[e] = (gs < ws_ + 1.0f) ? (ws_ - gs) : 0.0f;
                // hinge discontinuous at margin==1 -> exact f32 recompute later
                if (fabsf((gs - ws_) - 1.0f) < 0.125f && fixcap > 0) {
                    const int idx = atomicAdd(fixcnt, 1);
                    if (idx < fixcap) fixlist[idx] = e;
                }
            }
        }
        // next iteration reuses myh: same wave, ordered via lgkmcnt.
    }
}

// ---- exact f32 recompute of margin-boundary edges (~1e-3 of edges) ----
__global__ __launch_bounds__(256) void fixup_kernel(
    const float* __restrict__ fwd, const float* __restrict__ bwd,
    const int* __restrict__ gold_heads, const int* __restrict__ gold_rels,
    const float* __restrict__ WFOH, const float* __restrict__ WFOM,
    const float* __restrict__ rcatBias, const float* __restrict__ rhid2Layer,
    const float* __restrict__ rhid2Bias, const float* __restrict__ routLayer,
    const float* __restrict__ routBias,
    const int* __restrict__ fixcnt, const int* __restrict__ fixlist, int fixcap,
    float* __restrict__ out)
{
    __shared__ float fx_cat[256];
    __shared__ float fx_h[256];
    __shared__ float fx_h2[128];
    __shared__ float fx_p[256];
    int n = *fixcnt;
    if (n > fixcap) n = fixcap;
    const int tid = threadIdx.x;
    for (int i = blockIdx.x; i < n; i += gridDim.x) {
        const int e = fixlist[i];
        {
            const int head = gold_heads[e];
            fx_cat[tid] = (tid < 128) ? fwd[(size_t)head * 128 + tid]
                                      : bwd[(size_t)(e + 1) * 128 + (tid - 128)];
        }
        __syncthreads();
        {
            const float* base = (tid < 128) ? WFOH : WFOM;
            const int col = tid & 127;
            float s = 0.f;
            #pragma unroll 8
            for (int k = 0; k < 256; ++k) s += fx_cat[k] * base[k * 128 + col];
            fx_h[tid] = tanhf(s + rcatBias[tid]);
        }
        __syncthreads();
        {
            const int d = tid & 127, hh = tid >> 7;
            float s = 0.f;
            #pragma unroll 8
            for (int k = 128 * hh; k < 128 * hh + 128; ++k) s += fx_h[k] * rhid2Layer[k * 128 + d];
            fx_p[hh * 128 + d] = s;
        }
        __syncthreads();
        if (tid < 128) fx_h2[tid] = tanhf(fx_p[tid] + fx_p[128 + tid] + rhid2Bias[tid]);
        __syncthreads();
        {
            const int d = tid & 63, qq = tid >> 6;
            float s = 0.f;
            #pragma unroll 8
            for (int k = 32 * qq; k < 32 * qq + 32; ++k) s += fx_h2[k] * routLayer[k * 64 + d];
            fx_p[qq * 64 + d] = s;
        }
        __syncthreads();
        if (tid < 64) {
            const float v = fx_p[tid] + fx_p[64 + tid] + fx_p[128 + tid] + fx_p[192 + tid] + routBias[tid];
            const int gold = gold_rels[e];
            float gs = (tid == gold) ? v : -3.0e38f;
            float wv = (tid == gold) ? -3.0e38f : v;
            #pragma unroll
            for (int o = 1; o < 64; o <<= 1) {
                gs = fmaxf(gs, __shfl_xor(gs, o));
                wv = fmaxf(wv, __shfl_xor(wv, o));
            }
            if (tid == 0) out[e] = (gs < wv + 1.0f) ? (wv - gs) : 0.0f;
        }
        __syncthreads();
    }
}

extern "C" void kernel_launch(void* const* d_in, const int* in_sizes, int n_in,
                              void* d_out, int out_size, void* d_ws, size_t ws_size,
                              hipStream_t stream) {
    const float* fwd        = (const float*)d_in[0];
    const float* bwd        = (const float*)d_in[1];
    const int*   gold_heads = (const int*)d_in[2];
    const int*   gold_rels  = (const int*)d_in[3];
    const float* WFOH       = (const float*)d_in[4];
    const float* WFOM       = (const float*)d_in[5];
    const float* rcatBias   = (const float*)d_in[7];   // d_in[6] rhidBias unused by reference
    const float* rhid2      = (const float*)d_in[8];
    const float* rhid2Bias  = (const float*)d_in[9];
    const float* rout       = (const float*)d_in[10];
    const float* routBias   = (const float*)d_in[11];
    float* out = (float*)d_out;

    const int E = in_sizes[2];
    if (E <= 0) return;
    const int NT16 = (E + 15) / 16;
    int grid = (NT16 + 3) / 4;
    if (grid > 2560) grid = 2560;   // ~10 blocks/CU queued

    const size_t TAB = 212992;
    const int FIXCAP = 8192;
    const size_t FIX_BYTES = 4 + 4 * (size_t)FIXCAP;

    const bool pre = ws_size >= TAB + FIX_BYTES;
    int* fixcnt = nullptr;
    int* fixlist = nullptr;
    int fixcap = 0;
    if (pre) {
        fixcnt = (int*)((char*)d_ws + TAB);
        fixlist = fixcnt + 1;
        fixcap = FIXCAP;
    } else if (ws_size >= FIX_BYTES) {
        fixcnt = (int*)d_ws;
        fixlist = fixcnt + 1;
        fixcap = FIXCAP;
    }
    if (fixcap) hipMemsetAsync(fixcnt, 0, 4, stream);

    if (pre) {
        hipLaunchKernelGGL(preconv_kernel, dim3(52), dim3(256), 0, stream,
                           WFOH, WFOM, rhid2, rout, (char*)d_ws);
        hipLaunchKernelGGL((rel_kernel<true>), dim3(grid), dim3(256), 0, stream,
                           fwd, bwd, gold_heads, gold_rels, WFOH, WFOM, rcatBias,
                           rhid2, rhid2Bias, rout, routBias, (const char*)d_ws,
                           fixcnt, fixlist, fixcap, out, E, NT16);
    } else {
        hipLaunchKernelGGL((rel_kernel<false>), dim3(grid), dim3(256), 0, stream,
                           fwd, bwd, gold_heads, gold_rels, WFOH, WFOM, rcatBias,
                           rhid2, rhid2Bias, rout, routBias, (const char*)nullptr,
                           fixcnt, fixlist, fixcap, out, E, NT16);
    }
    if (fixcap) {
        hipLaunchKernelGGL(fixup_kernel, dim3(120), dim3(256), 0, stream,
                           fwd, bwd, gold_heads, gold_rels, WFOH, WFOM, rcatBias,
                           rhid2, rhid2Bias, rout, routBias,
                           fixcnt, fixlist, fixcap, out);
    }
}